// Round 5
// baseline (316.728 us; speedup 1.0000x reference)
//
#include <hip/hip_runtime.h>
#include <hip/hip_bf16.h>
#include <math.h>

// Dims (match reference)
#define NL_    2
#define LDIM   48
#define CDIM   16
#define BDIM   8
#define HDIM   64
#define PI_F   3.14159265358979323846f

// e_edge is an exact function of (species_s, species_r, d); tabulate.
#define GRID_D     8192
#define RC_F       2.0f
#define INV_STEP   ((float)GRID_D / RC_F)
#define TBL_STRIDE (GRID_D + 1)
#define NTAB       (4 * TBL_STRIDE)
#define TBL_BYTES  ((size_t)(NTAB + 4) * sizeof(float))

__device__ __forceinline__ float silu_f(float v) {
    float e = __expf(-v);
    return v * __builtin_amdgcn_rcpf(1.0f + e);
}
__device__ __forceinline__ float rlane(float v, int k) {
    return __uint_as_float(__builtin_amdgcn_readlane(__float_as_uint(v), k));
}

// ================= cooperative build: lane = neuron, readlane broadcast ============
// One wave (64 thr) per block; PTS d-points per block; weights live in VGPRs,
// preloaded once per block with fully-static indices (no scratch).
#define PTS   8
#define TPB_B 64

__launch_bounds__(TPB_B)
__global__ void build_table_v2(
    const float* __restrict__ W1, const float* __restrict__ b1,
    const float* __restrict__ W2, const float* __restrict__ b2,
    const float* __restrict__ Wv,
    const float* __restrict__ Wm1, const float* __restrict__ bm1,
    const float* __restrict__ Wm2, const float* __restrict__ bm2,
    const float* __restrict__ Wg, const float* __restrict__ Wn,
    const float* __restrict__ Wout, float* __restrict__ tbl)
{
    const int j    = threadIdx.x;
    const int base = blockIdx.x * PTS;

    float a1[PTS], xv[PTS], pv[PTS], cutv[PTS];

    // ---------------- stage 1: feat @ W1 + b1, silu (width 64) ----------------
    {
        float b1j  = b1[j];
        float w1r0 = W1[0*HDIM + j], w1r1 = W1[1*HDIM + j];
        float w1r2 = W1[2*HDIM + j], w1r3 = W1[3*HDIM + j];
        float w1b[BDIM];
        #pragma unroll
        for (int t = 0; t < BDIM; ++t) w1b[t] = W1[(4 + t)*HDIM + j];

        #pragma unroll
        for (int b = 0; b < PTS; ++b) {
            int gid = base + b;
            int g2  = gid < (NTAB + 4) ? gid : 0;
            int combo; float d;
            if (g2 < NTAB) { combo = g2 / TBL_STRIDE; d = (float)(g2 - combo*TBL_STRIDE) * (RC_F/(float)GRID_D); }
            else           { combo = g2 - NTAB;       d = 0.0f; }
            float inv_de = 1.0f / (d + 1e-9f);
            float tt  = fminf(d * 0.5f, 1.0f);
            cutv[b] = 0.5f * (__cosf(PI_F * tt) + 1.0f);
            float s1, c1; __sincosf(PI_F * d * 0.5f, &s1, &c1);

            float acc = b1j + ((combo >> 1) ? w1r1 : w1r0) + ((combo & 1) ? w1r3 : w1r2);
            float sn_1 = 0.0f, sn = s1;
            #pragma unroll
            for (int t = 0; t < BDIM; ++t) {
                acc = fmaf(sn * inv_de, w1b[t], acc);
                float s2 = 2.0f * c1 * sn - sn_1; sn_1 = sn; sn = s2;
            }
            a1[b] = silu_f(acc);
        }
    }

    // ---------------- stage 2: @ W2 + b2, * cut (64 -> 48) ----------------
    {
        float b2j = (j < LDIM) ? b2[j] : 0.0f;
        float w[HDIM];
        #pragma unroll
        for (int k = 0; k < HDIM; ++k) w[k] = (j < LDIM) ? W2[k*LDIM + j] : 0.0f;
        #pragma unroll
        for (int b = 0; b < PTS; ++b) {
            float acc = b2j;
            #pragma unroll
            for (int k = 0; k < HDIM; ++k) acc = fmaf(rlane(a1[b], k), w[k], acc);
            xv[b] = acc * cutv[b];
        }
    }

    // ---------------- p = x @ Wv (48 -> 16) ----------------
    {
        float w[LDIM];
        #pragma unroll
        for (int k = 0; k < LDIM; ++k) w[k] = (j < CDIM) ? Wv[k*CDIM + j] : 0.0f;
        #pragma unroll
        for (int b = 0; b < PTS; ++b) {
            float acc = 0.0f;
            #pragma unroll
            for (int k = 0; k < LDIM; ++k) acc = fmaf(rlane(xv[b], k), w[k], acc);
            pv[b] = acc;
        }
    }

    // ---------------- Allegro layers ----------------
    #pragma unroll
    for (int l = 0; l < NL_; ++l) {
        // mlp1: concat(x, inv) @ Wm1 + bm1, silu (64 -> 64)
        {
            float bj = bm1[l*HDIM + j];
            float w[HDIM];
            #pragma unroll
            for (int k = 0; k < HDIM; ++k) w[k] = Wm1[l*(LDIM+CDIM)*HDIM + k*HDIM + j];
            #pragma unroll
            for (int b = 0; b < PTS; ++b) {
                int gid = base + b;
                float uu = ((gid < (NTAB+4) ? gid : 0) < NTAB) ? 1.0f : 0.0f;
                float invb = uu * pv[b] * pv[b];      // valid at lanes < CDIM
                float acc = bj;
                #pragma unroll
                for (int k = 0; k < LDIM; ++k) acc = fmaf(rlane(xv[b], k), w[k], acc);
                #pragma unroll
                for (int k = LDIM; k < LDIM + CDIM; ++k) acc = fmaf(rlane(invb, k - LDIM), w[k], acc);
                a1[b] = silu_f(acc);
            }
        }
        // mlp2: @ Wm2 + bm2; x = (x + dx) * cut (64 -> 48)
        {
            float bj = (j < LDIM) ? bm2[l*LDIM + j] : 0.0f;
            float w[HDIM];
            #pragma unroll
            for (int k = 0; k < HDIM; ++k) w[k] = (j < LDIM) ? Wm2[l*HDIM*LDIM + k*LDIM + j] : 0.0f;
            #pragma unroll
            for (int b = 0; b < PTS; ++b) {
                float acc = bj;
                #pragma unroll
                for (int k = 0; k < HDIM; ++k) acc = fmaf(rlane(a1[b], k), w[k], acc);
                xv[b] = (xv[b] + acc) * cutv[b];
            }
        }
        // gate & new in one pass: lanes 0..15 -> g, lanes 16..31 -> nv (48 -> 16 x2)
        {
            float w[LDIM];
            #pragma unroll
            for (int k = 0; k < LDIM; ++k) {
                float v = 0.0f;
                if (j < CDIM)            v = Wg[l*LDIM*CDIM + k*CDIM + j];
                else if (j < 2*CDIM)     v = Wn[l*LDIM*CDIM + k*CDIM + (j - CDIM)];
                w[k] = v;
            }
            #pragma unroll
            for (int b = 0; b < PTS; ++b) {
                float acc = 0.0f;
                #pragma unroll
                for (int k = 0; k < LDIM; ++k) acc = fmaf(rlane(xv[b], k), w[k], acc);
                float nvs = __shfl(acc, (threadIdx.x & 63) + 16, 64); // lanes<16 pull nv
                pv[b] = fmaf(pv[b], acc, nvs);                        // valid at lanes<16
            }
        }
    }

    // ---------------- readout: eo = (x . Wout) * cut / 3 ----------------
    {
        float wo = (j < LDIM) ? Wout[j] : 0.0f;
        #pragma unroll
        for (int b = 0; b < PTS; ++b) {
            float v = xv[b] * wo;
            #pragma unroll
            for (int off = 1; off < 64; off <<= 1) v += __shfl_xor(v, off, 64);
            int gid = base + b;
            if (j == 0 && gid < NTAB + 4) tbl[gid] = v * cutv[b] * (1.0f / 3.0f);
        }
    }
}

// ================= edge pass: gather + lerp + scatter ==============================
#define TPB_E 256
__launch_bounds__(TPB_E)
__global__ void edge_scatter_kernel(
    const float* __restrict__ pos, const int* __restrict__ species,
    const int* __restrict__ senders, const int* __restrict__ receivers,
    const float* __restrict__ tbl, float* __restrict__ out, int E)
{
    int e = blockIdx.x * TPB_E + threadIdx.x;
    if (e >= E) return;
    int si = senders[e], ri = receivers[e];

    float rx = pos[3*ri+0] - pos[3*si+0];
    float ry = pos[3*ri+1] - pos[3*si+1];
    float rz = pos[3*ri+2] - pos[3*si+2];
    float d  = sqrtf(rx*rx + ry*ry + rz*rz);
    int combo = species[si] * 2 + species[ri];

    float eo;
    if (d > 0.0f) {
        float t = fminf(d * INV_STEP, (float)GRID_D);
        int i0 = (int)t;
        i0 = i0 < (GRID_D - 1) ? i0 : (GRID_D - 1);
        float f = t - (float)i0;
        const float* tb = tbl + combo * TBL_STRIDE + i0;
        float a = tb[0], b = tb[1];
        eo = fmaf(f, b - a, a);
    } else {
        eo = tbl[NTAB + combo];
    }
    atomicAdd(&out[ri], eo);
}

// ================= fallback (validated R3 direct kernel) if ws too small ===========
#define TPB 128
#define SLICE 65
__launch_bounds__(TPB)
__global__ void allegro_edge_kernel(
    const float* __restrict__ pos, const int* __restrict__ species,
    const int* __restrict__ senders, const int* __restrict__ receivers,
    const float* __restrict__ W1, const float* __restrict__ b1,
    const float* __restrict__ W2, const float* __restrict__ b2,
    const float* __restrict__ Wv,
    const float* __restrict__ Wm1, const float* __restrict__ bm1,
    const float* __restrict__ Wm2, const float* __restrict__ bm2,
    const float* __restrict__ Wg, const float* __restrict__ Wn,
    const float* __restrict__ Wout,
    float* __restrict__ out, int E)
{
    __shared__ float buf[TPB * SLICE];
    float* my = &buf[threadIdx.x * SLICE];
    int e = blockIdx.x * TPB + threadIdx.x;
    if (e >= E) return;
    int si = senders[e], ri = receivers[e];
    float rx = pos[3*ri+0] - pos[3*si+0];
    float ry = pos[3*ri+1] - pos[3*si+1];
    float rz = pos[3*ri+2] - pos[3*si+2];
    float d  = sqrtf(rx*rx + ry*ry + rz*rz);
    float inv_de = 1.0f / (d + 1e-9f);
    float ux = rx*inv_de, uy = ry*inv_de, uz = rz*inv_de;
    float uu = ux*ux + uy*uy + uz*uz;
    int zs = species[si], zr = species[ri];

    float tt  = fminf(d * 0.5f, 1.0f);
    float cut = 0.5f * (__cosf(PI_F * tt) + 1.0f);
    float k0 = PI_F * d * 0.5f;
    float s1, c1; __sincosf(k0, &s1, &c1);

    float acc[HDIM];
    #pragma unroll
    for (int jj = 0; jj < HDIM; ++jj) {
        float vs = zs ? W1[1*HDIM + jj] : W1[0*HDIM + jj];
        float vr = zr ? W1[3*HDIM + jj] : W1[2*HDIM + jj];
        acc[jj] = b1[jj] + vs + vr;
    }
    float sn_1 = 0.0f, sn = s1;
    #pragma unroll
    for (int bb = 0; bb < BDIM; ++bb) {
        float bv = sn * inv_de;
        #pragma unroll
        for (int jj = 0; jj < HDIM; ++jj) acc[jj] = fmaf(bv, W1[(4+bb)*HDIM + jj], acc[jj]);
        float s2 = 2.0f*c1*sn - sn_1; sn_1 = sn; sn = s2;
    }
    #pragma unroll
    for (int jj = 0; jj < HDIM; ++jj) my[jj] = silu_f(acc[jj]);

    float x[LDIM];
    #pragma unroll
    for (int jj = 0; jj < LDIM; ++jj) x[jj] = b2[jj];
    #pragma unroll 2
    for (int k = 0; k < HDIM; ++k) {
        float a = my[k];
        #pragma unroll
        for (int jj = 0; jj < LDIM; ++jj) x[jj] = fmaf(a, W2[k*LDIM + jj], x[jj]);
    }
    #pragma unroll
    for (int jj = 0; jj < LDIM; ++jj) { x[jj] *= cut; my[jj] = x[jj]; }

    float p[CDIM];
    #pragma unroll
    for (int c = 0; c < CDIM; ++c) p[c] = 0.0f;
    #pragma unroll 4
    for (int k = 0; k < LDIM; ++k) {
        float a = my[k];
        #pragma unroll
        for (int c = 0; c < CDIM; ++c) p[c] = fmaf(a, Wv[k*CDIM + c], p[c]);
    }

    #pragma unroll
    for (int l = 0; l < NL_; ++l) {
        const float* wm1 = Wm1 + l*(LDIM+CDIM)*HDIM;
        const float* wm2 = Wm2 + l*HDIM*LDIM;
        const float* wg  = Wg  + l*LDIM*CDIM;
        const float* wn  = Wn  + l*LDIM*CDIM;
        #pragma unroll
        for (int c = 0; c < CDIM; ++c) my[LDIM + c] = uu * p[c] * p[c];
        float h[HDIM];
        #pragma unroll
        for (int jj = 0; jj < HDIM; ++jj) h[jj] = bm1[l*HDIM + jj];
        #pragma unroll 2
        for (int k = 0; k < LDIM + CDIM; ++k) {
            float a = my[k];
            #pragma unroll
            for (int jj = 0; jj < HDIM; ++jj) h[jj] = fmaf(a, wm1[k*HDIM + jj], h[jj]);
        }
        #pragma unroll
        for (int jj = 0; jj < HDIM; ++jj) my[jj] = silu_f(h[jj]);
        float dx[LDIM];
        #pragma unroll
        for (int jj = 0; jj < LDIM; ++jj) dx[jj] = bm2[l*LDIM + jj];
        #pragma unroll 2
        for (int k = 0; k < HDIM; ++k) {
            float a = my[k];
            #pragma unroll
            for (int jj = 0; jj < LDIM; ++jj) dx[jj] = fmaf(a, wm2[k*LDIM + jj], dx[jj]);
        }
        #pragma unroll
        for (int jj = 0; jj < LDIM; ++jj) { x[jj] = (x[jj] + dx[jj]) * cut; my[jj] = x[jj]; }
        float g[CDIM], nv[CDIM];
        #pragma unroll
        for (int c = 0; c < CDIM; ++c) { g[c] = 0.0f; nv[c] = 0.0f; }
        #pragma unroll 4
        for (int k = 0; k < LDIM; ++k) {
            float a = my[k];
            #pragma unroll
            for (int c = 0; c < CDIM; ++c) {
                g[c]  = fmaf(a, wg[k*CDIM + c], g[c]);
                nv[c] = fmaf(a, wn[k*CDIM + c], nv[c]);
            }
        }
        #pragma unroll
        for (int c = 0; c < CDIM; ++c) p[c] = fmaf(p[c], g[c], nv[c]);
    }

    float eo = 0.0f;
    #pragma unroll
    for (int k = 0; k < LDIM; ++k) eo = fmaf(x[k], Wout[k], eo);
    eo *= cut * (1.0f / 3.0f);
    atomicAdd(&out[ri], eo);
}

extern "C" void kernel_launch(void* const* d_in, const int* in_sizes, int n_in,
                              void* d_out, int out_size, void* d_ws, size_t ws_size,
                              hipStream_t stream) {
    const float* pos      = (const float*)d_in[0];
    const int*   species  = (const int*)  d_in[1];
    const int*   senders  = (const int*)  d_in[2];
    const int*   receivers= (const int*)  d_in[3];
    const float* W1   = (const float*)d_in[4];
    const float* b1   = (const float*)d_in[5];
    const float* W2   = (const float*)d_in[6];
    const float* b2   = (const float*)d_in[7];
    const float* Wv   = (const float*)d_in[8];
    const float* Wm1  = (const float*)d_in[9];
    const float* bm1  = (const float*)d_in[10];
    const float* Wm2  = (const float*)d_in[11];
    const float* bm2  = (const float*)d_in[12];
    const float* Wg   = (const float*)d_in[13];
    const float* Wn   = (const float*)d_in[14];
    const float* Wout = (const float*)d_in[15];

    float* out = (float*)d_out;
    int N = out_size;
    int E = in_sizes[2];

    hipMemsetAsync(out, 0, (size_t)N * sizeof(float), stream);

    if (ws_size >= TBL_BYTES) {
        float* tbl = (float*)d_ws;
        int nblocks = (NTAB + 4 + PTS - 1) / PTS;   // 4097, exact (32776 = 4097*8)
        build_table_v2<<<nblocks, TPB_B, 0, stream>>>(
            W1, b1, W2, b2, Wv, Wm1, bm1, Wm2, bm2, Wg, Wn, Wout, tbl);
        edge_scatter_kernel<<<(E + TPB_E - 1) / TPB_E, TPB_E, 0, stream>>>(
            pos, species, senders, receivers, tbl, out, E);
    } else {
        allegro_edge_kernel<<<(E + TPB - 1) / TPB, TPB, 0, stream>>>(
            pos, species, senders, receivers,
            W1, b1, W2, b2, Wv, Wm1, bm1, Wm2, bm2, Wg, Wn, Wout, out, E);
    }
}

// Round 7
// 219.498 us; speedup vs baseline: 1.4430x; 1.4430x over previous
//
#include <hip/hip_runtime.h>
#include <hip/hip_bf16.h>
#include <math.h>

// Dims (match reference)
#define NL_    2
#define LDIM   48
#define CDIM   16
#define BDIM   8
#define HDIM   64
#define PI_F   3.14159265358979323846f

// e_edge is an exact function of (species_s, species_r, d); tabulate.
// GRID_D=2048: lerp err ~ (step^2/8)*F'' ~ 2e-5 rel — well inside tolerance.
#define GRID_D     2048
#define RC_F       2.0f
#define INV_STEP   ((float)GRID_D / RC_F)
#define TBL_STRIDE (GRID_D + 1)
#define NTAB       (4 * TBL_STRIDE)
#define TBL_BYTES  ((size_t)(NTAB + 4) * sizeof(float))

__device__ __forceinline__ float silu_f(float v) {
    float e = __expf(-v);
    return v * __builtin_amdgcn_rcpf(1.0f + e);
}
__device__ __forceinline__ float rlane(float v, int k) {
    return __uint_as_float(__builtin_amdgcn_readlane(__float_as_uint(v), k));
}

// ================= cooperative build: lane = neuron, readlane broadcast ============
// One wave per block, PTS d-points per block. GRID_D=2048, PTS=2 keeps the same
// 4100-wave grid as R5 (4 waves/SIMD TLP) but 1/4 the per-wave work.
#define PTS   2
#define TPB_B 64

__launch_bounds__(TPB_B)
__global__ void build_table_v2(
    const float* __restrict__ W1, const float* __restrict__ b1,
    const float* __restrict__ W2, const float* __restrict__ b2,
    const float* __restrict__ Wv,
    const float* __restrict__ Wm1, const float* __restrict__ bm1,
    const float* __restrict__ Wm2, const float* __restrict__ bm2,
    const float* __restrict__ Wg, const float* __restrict__ Wn,
    const float* __restrict__ Wout, float* __restrict__ tbl)
{
    const int j    = threadIdx.x;
    const int base = blockIdx.x * PTS;

    float a1[PTS], xv[PTS], pv[PTS], cutv[PTS];

    // ---------------- stage 1: feat @ W1 + b1, silu (width 64) ----------------
    {
        float b1j  = b1[j];
        float w1r0 = W1[0*HDIM + j], w1r1 = W1[1*HDIM + j];
        float w1r2 = W1[2*HDIM + j], w1r3 = W1[3*HDIM + j];
        float w1b[BDIM];
        #pragma unroll
        for (int t = 0; t < BDIM; ++t) w1b[t] = W1[(4 + t)*HDIM + j];

        #pragma unroll
        for (int b = 0; b < PTS; ++b) {
            int gid = base + b;
            int g2  = gid < (NTAB + 4) ? gid : 0;
            int combo; float d;
            if (g2 < NTAB) { combo = g2 / TBL_STRIDE; d = (float)(g2 - combo*TBL_STRIDE) * (RC_F/(float)GRID_D); }
            else           { combo = g2 - NTAB;       d = 0.0f; }
            float inv_de = 1.0f / (d + 1e-9f);
            float tt  = fminf(d * 0.5f, 1.0f);
            cutv[b] = 0.5f * (__cosf(PI_F * tt) + 1.0f);
            float s1, c1; __sincosf(PI_F * d * 0.5f, &s1, &c1);

            float acc = b1j + ((combo >> 1) ? w1r1 : w1r0) + ((combo & 1) ? w1r3 : w1r2);
            float sn_1 = 0.0f, sn = s1;
            #pragma unroll
            for (int t = 0; t < BDIM; ++t) {
                acc = fmaf(sn * inv_de, w1b[t], acc);
                float s2 = 2.0f * c1 * sn - sn_1; sn_1 = sn; sn = s2;
            }
            a1[b] = silu_f(acc);
        }
    }

    // ---------------- stage 2: @ W2 + b2, * cut (64 -> 48) ----------------
    {
        float b2j = (j < LDIM) ? b2[j] : 0.0f;
        float w[HDIM];
        #pragma unroll
        for (int k = 0; k < HDIM; ++k) w[k] = (j < LDIM) ? W2[k*LDIM + j] : 0.0f;
        #pragma unroll
        for (int b = 0; b < PTS; ++b) {
            float acc = b2j;
            #pragma unroll
            for (int k = 0; k < HDIM; ++k) acc = fmaf(rlane(a1[b], k), w[k], acc);
            xv[b] = acc * cutv[b];
        }
    }

    // ---------------- p = x @ Wv (48 -> 16) ----------------
    {
        float w[LDIM];
        #pragma unroll
        for (int k = 0; k < LDIM; ++k) w[k] = (j < CDIM) ? Wv[k*CDIM + j] : 0.0f;
        #pragma unroll
        for (int b = 0; b < PTS; ++b) {
            float acc = 0.0f;
            #pragma unroll
            for (int k = 0; k < LDIM; ++k) acc = fmaf(rlane(xv[b], k), w[k], acc);
            pv[b] = acc;
        }
    }

    // ---------------- Allegro layers ----------------
    #pragma unroll
    for (int l = 0; l < NL_; ++l) {
        // mlp1: concat(x, inv) @ Wm1 + bm1, silu (64 -> 64)
        {
            float bj = bm1[l*HDIM + j];
            float w[HDIM];
            #pragma unroll
            for (int k = 0; k < HDIM; ++k) w[k] = Wm1[l*(LDIM+CDIM)*HDIM + k*HDIM + j];
            #pragma unroll
            for (int b = 0; b < PTS; ++b) {
                int gid = base + b;
                float uu = ((gid < (NTAB+4) ? gid : 0) < NTAB) ? 1.0f : 0.0f;
                float invb = uu * pv[b] * pv[b];      // valid at lanes < CDIM
                float acc = bj;
                #pragma unroll
                for (int k = 0; k < LDIM; ++k) acc = fmaf(rlane(xv[b], k), w[k], acc);
                #pragma unroll
                for (int k = LDIM; k < LDIM + CDIM; ++k) acc = fmaf(rlane(invb, k - LDIM), w[k], acc);
                a1[b] = silu_f(acc);
            }
        }
        // mlp2: @ Wm2 + bm2; x = (x + dx) * cut (64 -> 48)
        {
            float bj = (j < LDIM) ? bm2[l*LDIM + j] : 0.0f;
            float w[HDIM];
            #pragma unroll
            for (int k = 0; k < HDIM; ++k) w[k] = (j < LDIM) ? Wm2[l*HDIM*LDIM + k*LDIM + j] : 0.0f;
            #pragma unroll
            for (int b = 0; b < PTS; ++b) {
                float acc = bj;
                #pragma unroll
                for (int k = 0; k < HDIM; ++k) acc = fmaf(rlane(a1[b], k), w[k], acc);
                xv[b] = (xv[b] + acc) * cutv[b];
            }
        }
        // gate & new in one pass: lanes 0..15 -> g, lanes 16..31 -> nv (48 -> 16 x2)
        {
            float w[LDIM];
            #pragma unroll
            for (int k = 0; k < LDIM; ++k) {
                float v = 0.0f;
                if (j < CDIM)            v = Wg[l*LDIM*CDIM + k*CDIM + j];
                else if (j < 2*CDIM)     v = Wn[l*LDIM*CDIM + k*CDIM + (j - CDIM)];
                w[k] = v;
            }
            #pragma unroll
            for (int b = 0; b < PTS; ++b) {
                float acc = 0.0f;
                #pragma unroll
                for (int k = 0; k < LDIM; ++k) acc = fmaf(rlane(xv[b], k), w[k], acc);
                float nvs = __shfl(acc, (threadIdx.x & 63) + 16, 64); // lanes<16 pull nv
                pv[b] = fmaf(pv[b], acc, nvs);                        // valid at lanes<16
            }
        }
    }

    // ---------------- readout: eo = (x . Wout) * cut / 3 ----------------
    {
        float wo = (j < LDIM) ? Wout[j] : 0.0f;
        #pragma unroll
        for (int b = 0; b < PTS; ++b) {
            float v = xv[b] * wo;
            #pragma unroll
            for (int off = 1; off < 64; off <<= 1) v += __shfl_xor(v, off, 64);
            int gid = base + b;
            if (j == 0 && gid < NTAB + 4) tbl[gid] = v * cutv[b] * (1.0f / 3.0f);
        }
    }
}

// ================= edge pass: gather + lerp + scatter ==============================
#define TPB_E 256
__launch_bounds__(TPB_E)
__global__ void edge_scatter_kernel(
    const float* __restrict__ pos, const int* __restrict__ species,
    const int* __restrict__ senders, const int* __restrict__ receivers,
    const float* __restrict__ tbl, float* __restrict__ out, int E)
{
    int e = blockIdx.x * TPB_E + threadIdx.x;
    if (e >= E) return;
    int si = senders[e], ri = receivers[e];

    float rx = pos[3*ri+0] - pos[3*si+0];
    float ry = pos[3*ri+1] - pos[3*si+1];
    float rz = pos[3*ri+2] - pos[3*si+2];
    float d  = sqrtf(rx*rx + ry*ry + rz*rz);
    int combo = species[si] * 2 + species[ri];

    float eo;
    if (d > 0.0f) {
        float t = fminf(d * INV_STEP, (float)GRID_D);
        int i0 = (int)t;
        i0 = i0 < (GRID_D - 1) ? i0 : (GRID_D - 1);
        float f = t - (float)i0;
        const float* tb = tbl + combo * TBL_STRIDE + i0;
        float a = tb[0], b = tb[1];
        eo = fmaf(f, b - a, a);
    } else {
        eo = tbl[NTAB + combo];
    }
    atomicAdd(&out[ri], eo);
}

// ================= fallback (validated R3 direct kernel) if ws too small ===========
#define TPB 128
#define SLICE 65
__launch_bounds__(TPB)
__global__ void allegro_edge_kernel(
    const float* __restrict__ pos, const int* __restrict__ species,
    const int* __restrict__ senders, const int* __restrict__ receivers,
    const float* __restrict__ W1, const float* __restrict__ b1,
    const float* __restrict__ W2, const float* __restrict__ b2,
    const float* __restrict__ Wv,
    const float* __restrict__ Wm1, const float* __restrict__ bm1,
    const float* __restrict__ Wm2, const float* __restrict__ bm2,
    const float* __restrict__ Wg, const float* __restrict__ Wn,
    const float* __restrict__ Wout,
    float* __restrict__ out, int E)
{
    __shared__ float buf[TPB * SLICE];
    float* my = &buf[threadIdx.x * SLICE];
    int e = blockIdx.x * TPB + threadIdx.x;
    if (e >= E) return;
    int si = senders[e], ri = receivers[e];
    float rx = pos[3*ri+0] - pos[3*si+0];
    float ry = pos[3*ri+1] - pos[3*si+1];
    float rz = pos[3*ri+2] - pos[3*si+2];
    float d  = sqrtf(rx*rx + ry*ry + rz*rz);
    float inv_de = 1.0f / (d + 1e-9f);
    float ux = rx*inv_de, uy = ry*inv_de, uz = rz*inv_de;
    float uu = ux*ux + uy*uy + uz*uz;
    int zs = species[si], zr = species[ri];

    float tt  = fminf(d * 0.5f, 1.0f);
    float cut = 0.5f * (__cosf(PI_F * tt) + 1.0f);
    float k0 = PI_F * d * 0.5f;
    float s1, c1; __sincosf(k0, &s1, &c1);

    float acc[HDIM];
    #pragma unroll
    for (int jj = 0; jj < HDIM; ++jj) {
        float vs = zs ? W1[1*HDIM + jj] : W1[0*HDIM + jj];
        float vr = zr ? W1[3*HDIM + jj] : W1[2*HDIM + jj];
        acc[jj] = b1[jj] + vs + vr;
    }
    float sn_1 = 0.0f, sn = s1;
    #pragma unroll
    for (int bb = 0; bb < BDIM; ++bb) {
        float bv = sn * inv_de;
        #pragma unroll
        for (int jj = 0; jj < HDIM; ++jj) acc[jj] = fmaf(bv, W1[(4+bb)*HDIM + jj], acc[jj]);
        float s2 = 2.0f*c1*sn - sn_1; sn_1 = sn; sn = s2;
    }
    #pragma unroll
    for (int jj = 0; jj < HDIM; ++jj) my[jj] = silu_f(acc[jj]);

    float x[LDIM];
    #pragma unroll
    for (int jj = 0; jj < LDIM; ++jj) x[jj] = b2[jj];
    #pragma unroll 2
    for (int k = 0; k < HDIM; ++k) {
        float a = my[k];
        #pragma unroll
        for (int jj = 0; jj < LDIM; ++jj) x[jj] = fmaf(a, W2[k*LDIM + jj], x[jj]);
    }
    #pragma unroll
    for (int jj = 0; jj < LDIM; ++jj) { x[jj] *= cut; my[jj] = x[jj]; }

    float p[CDIM];
    #pragma unroll
    for (int c = 0; c < CDIM; ++c) p[c] = 0.0f;
    #pragma unroll 4
    for (int k = 0; k < LDIM; ++k) {
        float a = my[k];
        #pragma unroll
        for (int c = 0; c < CDIM; ++c) p[c] = fmaf(a, Wv[k*CDIM + c], p[c]);
    }

    #pragma unroll
    for (int l = 0; l < NL_; ++l) {
        const float* wm1 = Wm1 + l*(LDIM+CDIM)*HDIM;
        const float* wm2 = Wm2 + l*HDIM*LDIM;
        const float* wg  = Wg  + l*LDIM*CDIM;
        const float* wn  = Wn  + l*LDIM*CDIM;
        #pragma unroll
        for (int c = 0; c < CDIM; ++c) my[LDIM + c] = uu * p[c] * p[c];
        float h[HDIM];
        #pragma unroll
        for (int jj = 0; jj < HDIM; ++jj) h[jj] = bm1[l*HDIM + jj];
        #pragma unroll 2
        for (int k = 0; k < LDIM + CDIM; ++k) {
            float a = my[k];
            #pragma unroll
            for (int jj = 0; jj < HDIM; ++jj) h[jj] = fmaf(a, wm1[k*HDIM + jj], h[jj]);
        }
        #pragma unroll
        for (int jj = 0; jj < HDIM; ++jj) my[jj] = silu_f(h[jj]);
        float dx[LDIM];
        #pragma unroll
        for (int jj = 0; jj < LDIM; ++jj) dx[jj] = bm2[l*LDIM + jj];
        #pragma unroll 2
        for (int k = 0; k < HDIM; ++k) {
            float a = my[k];
            #pragma unroll
            for (int jj = 0; jj < LDIM; ++jj) dx[jj] = fmaf(a, wm2[k*LDIM + jj], dx[jj]);
        }
        #pragma unroll
        for (int jj = 0; jj < LDIM; ++jj) { x[jj] = (x[jj] + dx[jj]) * cut; my[jj] = x[jj]; }
        float g[CDIM], nv[CDIM];
        #pragma unroll
        for (int c = 0; c < CDIM; ++c) { g[c] = 0.0f; nv[c] = 0.0f; }
        #pragma unroll 4
        for (int k = 0; k < LDIM; ++k) {
            float a = my[k];
            #pragma unroll
            for (int c = 0; c < CDIM; ++c) {
                g[c]  = fmaf(a, wg[k*CDIM + c], g[c]);
                nv[c] = fmaf(a, wn[k*CDIM + c], nv[c]);
            }
        }
        #pragma unroll
        for (int c = 0; c < CDIM; ++c) p[c] = fmaf(p[c], g[c], nv[c]);
    }

    float eo = 0.0f;
    #pragma unroll
    for (int k = 0; k < LDIM; ++k) eo = fmaf(x[k], Wout[k], eo);
    eo *= cut * (1.0f / 3.0f);
    atomicAdd(&out[ri], eo);
}

extern "C" void kernel_launch(void* const* d_in, const int* in_sizes, int n_in,
                              void* d_out, int out_size, void* d_ws, size_t ws_size,
                              hipStream_t stream) {
    const float* pos      = (const float*)d_in[0];
    const int*   species  = (const int*)  d_in[1];
    const int*   senders  = (const int*)  d_in[2];
    const int*   receivers= (const int*)  d_in[3];
    const float* W1   = (const float*)d_in[4];
    const float* b1   = (const float*)d_in[5];
    const float* W2   = (const float*)d_in[6];
    const float* b2   = (const float*)d_in[7];
    const float* Wv   = (const float*)d_in[8];
    const float* Wm1  = (const float*)d_in[9];
    const float* bm1  = (const float*)d_in[10];
    const float* Wm2  = (const float*)d_in[11];
    const float* bm2  = (const float*)d_in[12];
    const float* Wg   = (const float*)d_in[13];
    const float* Wn   = (const float*)d_in[14];
    const float* Wout = (const float*)d_in[15];

    float* out = (float*)d_out;
    int N = out_size;
    int E = in_sizes[2];

    hipMemsetAsync(out, 0, (size_t)N * sizeof(float), stream);

    if (ws_size >= TBL_BYTES) {
        float* tbl = (float*)d_ws;
        int nblocks = (NTAB + 4 + PTS - 1) / PTS;   // 4100 waves -> 4/SIMD
        build_table_v2<<<nblocks, TPB_B, 0, stream>>>(
            W1, b1, W2, b2, Wv, Wm1, bm1, Wm2, bm2, Wg, Wn, Wout, tbl);
        edge_scatter_kernel<<<(E + TPB_E - 1) / TPB_E, TPB_E, 0, stream>>>(
            pos, species, senders, receivers, tbl, out, E);
    } else {
        allegro_edge_kernel<<<(E + TPB - 1) / TPB, TPB, 0, stream>>>(
            pos, species, senders, receivers,
            W1, b1, W2, b2, Wv, Wm1, bm1, Wm2, bm2, Wg, Wn, Wout, out, E);
    }
}

// Round 8
// 218.614 us; speedup vs baseline: 1.4488x; 1.0040x over previous
//
#include <hip/hip_runtime.h>
#include <hip/hip_bf16.h>
#include <math.h>

// Dims (match reference)
#define NL_    2
#define LDIM   48
#define CDIM   16
#define BDIM   8
#define HDIM   64
#define PI_F   3.14159265358979323846f

// e_edge is an exact function of (species_s, species_r, d); tabulate.
// GRID_D=2048 passed with absmax=16 (absmax tracks lerp err; don't shrink further).
#define GRID_D     2048
#define RC_F       2.0f
#define INV_STEP   ((float)GRID_D / RC_F)
#define TBL_STRIDE (GRID_D + 1)
#define NTAB       (4 * TBL_STRIDE)
#define TBL_BYTES  ((size_t)(NTAB + 4) * sizeof(float))

__device__ __forceinline__ float silu_f(float v) {
    float e = __expf(-v);
    return v * __builtin_amdgcn_rcpf(1.0f + e);
}
__device__ __forceinline__ float rlane(float v, int k) {
    return __uint_as_float(__builtin_amdgcn_readlane(__float_as_uint(v), k));
}

// ================= cooperative build: lane = neuron, readlane broadcast ============
// One wave per block, PTS=2 points (4100 blocks -> ~4 waves/SIMD).
// 2-way k-split accumulators halve the FMA dependency chains.
#define PTS   2
#define TPB_B 64

__launch_bounds__(TPB_B)
__global__ void build_table_v2(
    const float* __restrict__ W1, const float* __restrict__ b1,
    const float* __restrict__ W2, const float* __restrict__ b2,
    const float* __restrict__ Wv,
    const float* __restrict__ Wm1, const float* __restrict__ bm1,
    const float* __restrict__ Wm2, const float* __restrict__ bm2,
    const float* __restrict__ Wg, const float* __restrict__ Wn,
    const float* __restrict__ Wout, float* __restrict__ tbl)
{
    const int j    = threadIdx.x;
    const int base = blockIdx.x * PTS;

    float a1[PTS], xv[PTS], pv[PTS], cutv[PTS];

    // ---------------- stage 1: feat @ W1 + b1, silu (width 64) ----------------
    {
        float b1j  = b1[j];
        float w1r0 = W1[0*HDIM + j], w1r1 = W1[1*HDIM + j];
        float w1r2 = W1[2*HDIM + j], w1r3 = W1[3*HDIM + j];
        float w1b[BDIM];
        #pragma unroll
        for (int t = 0; t < BDIM; ++t) w1b[t] = W1[(4 + t)*HDIM + j];

        #pragma unroll
        for (int b = 0; b < PTS; ++b) {
            int gid = base + b;
            int g2  = gid < (NTAB + 4) ? gid : 0;
            int combo; float d;
            if (g2 < NTAB) { combo = g2 / TBL_STRIDE; d = (float)(g2 - combo*TBL_STRIDE) * (RC_F/(float)GRID_D); }
            else           { combo = g2 - NTAB;       d = 0.0f; }
            float inv_de = 1.0f / (d + 1e-9f);
            float tt  = fminf(d * 0.5f, 1.0f);
            cutv[b] = 0.5f * (__cosf(PI_F * tt) + 1.0f);
            float s1, c1; __sincosf(PI_F * d * 0.5f, &s1, &c1);

            float acc = b1j + ((combo >> 1) ? w1r1 : w1r0) + ((combo & 1) ? w1r3 : w1r2);
            float sn_1 = 0.0f, sn = s1;
            #pragma unroll
            for (int t = 0; t < BDIM; ++t) {
                acc = fmaf(sn * inv_de, w1b[t], acc);
                float s2 = 2.0f * c1 * sn - sn_1; sn_1 = sn; sn = s2;
            }
            a1[b] = silu_f(acc);
        }
    }

    // ---------------- stage 2: @ W2 + b2, * cut (64 -> 48) ----------------
    {
        float b2j = (j < LDIM) ? b2[j] : 0.0f;
        float w[HDIM];
        #pragma unroll
        for (int k = 0; k < HDIM; ++k) w[k] = (j < LDIM) ? W2[k*LDIM + j] : 0.0f;
        #pragma unroll
        for (int b = 0; b < PTS; ++b) {
            float ac0 = b2j, ac1 = 0.0f;
            #pragma unroll
            for (int k = 0; k < HDIM; k += 2) {
                ac0 = fmaf(rlane(a1[b], k),     w[k],     ac0);
                ac1 = fmaf(rlane(a1[b], k + 1), w[k + 1], ac1);
            }
            xv[b] = (ac0 + ac1) * cutv[b];
        }
    }

    // ---------------- p = x @ Wv (48 -> 16) ----------------
    {
        float w[LDIM];
        #pragma unroll
        for (int k = 0; k < LDIM; ++k) w[k] = (j < CDIM) ? Wv[k*CDIM + j] : 0.0f;
        #pragma unroll
        for (int b = 0; b < PTS; ++b) {
            float ac0 = 0.0f, ac1 = 0.0f;
            #pragma unroll
            for (int k = 0; k < LDIM; k += 2) {
                ac0 = fmaf(rlane(xv[b], k),     w[k],     ac0);
                ac1 = fmaf(rlane(xv[b], k + 1), w[k + 1], ac1);
            }
            pv[b] = ac0 + ac1;
        }
    }

    // ---------------- Allegro layers ----------------
    #pragma unroll
    for (int l = 0; l < NL_; ++l) {
        // mlp1: concat(x, inv) @ Wm1 + bm1, silu (64 -> 64)
        {
            float bj = bm1[l*HDIM + j];
            float w[HDIM];
            #pragma unroll
            for (int k = 0; k < HDIM; ++k) w[k] = Wm1[l*(LDIM+CDIM)*HDIM + k*HDIM + j];
            #pragma unroll
            for (int b = 0; b < PTS; ++b) {
                int gid = base + b;
                float uu = ((gid < (NTAB+4) ? gid : 0) < NTAB) ? 1.0f : 0.0f;
                float invb = uu * pv[b] * pv[b];      // valid at lanes < CDIM
                float ac0 = bj, ac1 = 0.0f;
                #pragma unroll
                for (int k = 0; k < LDIM; k += 2) {
                    ac0 = fmaf(rlane(xv[b], k),     w[k],     ac0);
                    ac1 = fmaf(rlane(xv[b], k + 1), w[k + 1], ac1);
                }
                #pragma unroll
                for (int k = LDIM; k < LDIM + CDIM; k += 2) {
                    ac0 = fmaf(rlane(invb, k - LDIM),     w[k],     ac0);
                    ac1 = fmaf(rlane(invb, k - LDIM + 1), w[k + 1], ac1);
                }
                a1[b] = silu_f(ac0 + ac1);
            }
        }
        // mlp2: @ Wm2 + bm2; x = (x + dx) * cut (64 -> 48)
        {
            float bj = (j < LDIM) ? bm2[l*LDIM + j] : 0.0f;
            float w[HDIM];
            #pragma unroll
            for (int k = 0; k < HDIM; ++k) w[k] = (j < LDIM) ? Wm2[l*HDIM*LDIM + k*LDIM + j] : 0.0f;
            #pragma unroll
            for (int b = 0; b < PTS; ++b) {
                float ac0 = bj, ac1 = 0.0f;
                #pragma unroll
                for (int k = 0; k < HDIM; k += 2) {
                    ac0 = fmaf(rlane(a1[b], k),     w[k],     ac0);
                    ac1 = fmaf(rlane(a1[b], k + 1), w[k + 1], ac1);
                }
                xv[b] = (xv[b] + ac0 + ac1) * cutv[b];
            }
        }
        // gate & new in one pass: lanes 0..15 -> g, lanes 16..31 -> nv (48 -> 16 x2)
        {
            float w[LDIM];
            #pragma unroll
            for (int k = 0; k < LDIM; ++k) {
                float v = 0.0f;
                if (j < CDIM)            v = Wg[l*LDIM*CDIM + k*CDIM + j];
                else if (j < 2*CDIM)     v = Wn[l*LDIM*CDIM + k*CDIM + (j - CDIM)];
                w[k] = v;
            }
            #pragma unroll
            for (int b = 0; b < PTS; ++b) {
                float ac0 = 0.0f, ac1 = 0.0f;
                #pragma unroll
                for (int k = 0; k < LDIM; k += 2) {
                    ac0 = fmaf(rlane(xv[b], k),     w[k],     ac0);
                    ac1 = fmaf(rlane(xv[b], k + 1), w[k + 1], ac1);
                }
                float acc = ac0 + ac1;
                float nvs = __shfl(acc, (threadIdx.x & 63) + 16, 64); // lanes<16 pull nv
                pv[b] = fmaf(pv[b], acc, nvs);                        // valid at lanes<16
            }
        }
    }

    // ---------------- readout: eo = (x . Wout) * cut / 3 ----------------
    {
        float wo = (j < LDIM) ? Wout[j] : 0.0f;
        #pragma unroll
        for (int b = 0; b < PTS; ++b) {
            float v = xv[b] * wo;
            #pragma unroll
            for (int off = 1; off < 64; off <<= 1) v += __shfl_xor(v, off, 64);
            int gid = base + b;
            if (j == 0 && gid < NTAB + 4) tbl[gid] = v * cutv[b] * (1.0f / 3.0f);
        }
    }
}

// ================= pos+species packer: [N] float4 (x,y,z,species) =================
__global__ void pack_pos4(const float* __restrict__ pos, const int* __restrict__ species,
                          float4* __restrict__ pos4, int N) {
    int i = blockIdx.x * blockDim.x + threadIdx.x;
    if (i < N) {
        pos4[i] = make_float4(pos[3*i+0], pos[3*i+1], pos[3*i+2], (float)species[i]);
    }
}

// ================= edge pass v2: 2 edges/thread, float4 gathers ====================
#define TPB_E 256
__device__ __forceinline__ float edge_eval(const float4& ps, const float4& pr,
                                           const float* __restrict__ tbl) {
    float rx = pr.x - ps.x, ry = pr.y - ps.y, rz = pr.z - ps.z;
    float d  = sqrtf(rx*rx + ry*ry + rz*rz);
    int combo = (int)ps.w * 2 + (int)pr.w;
    if (d > 0.0f) {
        float t = fminf(d * INV_STEP, (float)GRID_D);
        int i0 = (int)t;
        i0 = i0 < (GRID_D - 1) ? i0 : (GRID_D - 1);
        float f = t - (float)i0;
        const float* tb = tbl + combo * TBL_STRIDE + i0;
        float a = tb[0], b = tb[1];
        return fmaf(f, b - a, a);
    }
    return tbl[NTAB + combo];
}

__launch_bounds__(TPB_E)
__global__ void edge_scatter_v2(
    const float4* __restrict__ pos4,
    const int* __restrict__ senders, const int* __restrict__ receivers,
    const float* __restrict__ tbl, float* __restrict__ out, int E)
{
    int t  = blockIdx.x * TPB_E + threadIdx.x;
    int e0 = t * 2;
    if (e0 >= E) return;
    if (e0 + 1 < E) {
        int2 s2 = *reinterpret_cast<const int2*>(senders + e0);
        int2 r2 = *reinterpret_cast<const int2*>(receivers + e0);
        float4 ps0 = pos4[s2.x], pr0 = pos4[r2.x];
        float4 ps1 = pos4[s2.y], pr1 = pos4[r2.y];
        float eo0 = edge_eval(ps0, pr0, tbl);
        float eo1 = edge_eval(ps1, pr1, tbl);
        atomicAdd(&out[r2.x], eo0);
        atomicAdd(&out[r2.y], eo1);
    } else {
        int s = senders[e0], r = receivers[e0];
        float eo = edge_eval(pos4[s], pos4[r], tbl);
        atomicAdd(&out[r], eo);
    }
}

// ================= edge pass (tbl-only fallback, R6-validated) =====================
__launch_bounds__(TPB_E)
__global__ void edge_scatter_kernel(
    const float* __restrict__ pos, const int* __restrict__ species,
    const int* __restrict__ senders, const int* __restrict__ receivers,
    const float* __restrict__ tbl, float* __restrict__ out, int E)
{
    int e = blockIdx.x * TPB_E + threadIdx.x;
    if (e >= E) return;
    int si = senders[e], ri = receivers[e];

    float rx = pos[3*ri+0] - pos[3*si+0];
    float ry = pos[3*ri+1] - pos[3*si+1];
    float rz = pos[3*ri+2] - pos[3*si+2];
    float d  = sqrtf(rx*rx + ry*ry + rz*rz);
    int combo = species[si] * 2 + species[ri];

    float eo;
    if (d > 0.0f) {
        float t = fminf(d * INV_STEP, (float)GRID_D);
        int i0 = (int)t;
        i0 = i0 < (GRID_D - 1) ? i0 : (GRID_D - 1);
        float f = t - (float)i0;
        const float* tb = tbl + combo * TBL_STRIDE + i0;
        float a = tb[0], b = tb[1];
        eo = fmaf(f, b - a, a);
    } else {
        eo = tbl[NTAB + combo];
    }
    atomicAdd(&out[ri], eo);
}

// ================= fallback (validated R3 direct kernel) if ws too small ===========
#define TPB 128
#define SLICE 65
__launch_bounds__(TPB)
__global__ void allegro_edge_kernel(
    const float* __restrict__ pos, const int* __restrict__ species,
    const int* __restrict__ senders, const int* __restrict__ receivers,
    const float* __restrict__ W1, const float* __restrict__ b1,
    const float* __restrict__ W2, const float* __restrict__ b2,
    const float* __restrict__ Wv,
    const float* __restrict__ Wm1, const float* __restrict__ bm1,
    const float* __restrict__ Wm2, const float* __restrict__ bm2,
    const float* __restrict__ Wg, const float* __restrict__ Wn,
    const float* __restrict__ Wout,
    float* __restrict__ out, int E)
{
    __shared__ float buf[TPB * SLICE];
    float* my = &buf[threadIdx.x * SLICE];
    int e = blockIdx.x * TPB + threadIdx.x;
    if (e >= E) return;
    int si = senders[e], ri = receivers[e];
    float rx = pos[3*ri+0] - pos[3*si+0];
    float ry = pos[3*ri+1] - pos[3*si+1];
    float rz = pos[3*ri+2] - pos[3*si+2];
    float d  = sqrtf(rx*rx + ry*ry + rz*rz);
    float inv_de = 1.0f / (d + 1e-9f);
    float ux = rx*inv_de, uy = ry*inv_de, uz = rz*inv_de;
    float uu = ux*ux + uy*uy + uz*uz;
    int zs = species[si], zr = species[ri];

    float tt  = fminf(d * 0.5f, 1.0f);
    float cut = 0.5f * (__cosf(PI_F * tt) + 1.0f);
    float k0 = PI_F * d * 0.5f;
    float s1, c1; __sincosf(k0, &s1, &c1);

    float acc[HDIM];
    #pragma unroll
    for (int jj = 0; jj < HDIM; ++jj) {
        float vs = zs ? W1[1*HDIM + jj] : W1[0*HDIM + jj];
        float vr = zr ? W1[3*HDIM + jj] : W1[2*HDIM + jj];
        acc[jj] = b1[jj] + vs + vr;
    }
    float sn_1 = 0.0f, sn = s1;
    #pragma unroll
    for (int bb = 0; bb < BDIM; ++bb) {
        float bv = sn * inv_de;
        #pragma unroll
        for (int jj = 0; jj < HDIM; ++jj) acc[jj] = fmaf(bv, W1[(4+bb)*HDIM + jj], acc[jj]);
        float s2 = 2.0f*c1*sn - sn_1; sn_1 = sn; sn = s2;
    }
    #pragma unroll
    for (int jj = 0; jj < HDIM; ++jj) my[jj] = silu_f(acc[jj]);

    float x[LDIM];
    #pragma unroll
    for (int jj = 0; jj < LDIM; ++jj) x[jj] = b2[jj];
    #pragma unroll 2
    for (int k = 0; k < HDIM; ++k) {
        float a = my[k];
        #pragma unroll
        for (int jj = 0; jj < LDIM; ++jj) x[jj] = fmaf(a, W2[k*LDIM + jj], x[jj]);
    }
    #pragma unroll
    for (int jj = 0; jj < LDIM; ++jj) { x[jj] *= cut; my[jj] = x[jj]; }

    float p[CDIM];
    #pragma unroll
    for (int c = 0; c < CDIM; ++c) p[c] = 0.0f;
    #pragma unroll 4
    for (int k = 0; k < LDIM; ++k) {
        float a = my[k];
        #pragma unroll
        for (int c = 0; c < CDIM; ++c) p[c] = fmaf(a, Wv[k*CDIM + c], p[c]);
    }

    #pragma unroll
    for (int l = 0; l < NL_; ++l) {
        const float* wm1 = Wm1 + l*(LDIM+CDIM)*HDIM;
        const float* wm2 = Wm2 + l*HDIM*LDIM;
        const float* wg  = Wg  + l*LDIM*CDIM;
        const float* wn  = Wn  + l*LDIM*CDIM;
        #pragma unroll
        for (int c = 0; c < CDIM; ++c) my[LDIM + c] = uu * p[c] * p[c];
        float h[HDIM];
        #pragma unroll
        for (int jj = 0; jj < HDIM; ++jj) h[jj] = bm1[l*HDIM + jj];
        #pragma unroll 2
        for (int k = 0; k < LDIM + CDIM; ++k) {
            float a = my[k];
            #pragma unroll
            for (int jj = 0; jj < HDIM; ++jj) h[jj] = fmaf(a, wm1[k*HDIM + jj], h[jj]);
        }
        #pragma unroll
        for (int jj = 0; jj < HDIM; ++jj) my[jj] = silu_f(h[jj]);
        float dx[LDIM];
        #pragma unroll
        for (int jj = 0; jj < LDIM; ++jj) dx[jj] = bm2[l*LDIM + jj];
        #pragma unroll 2
        for (int k = 0; k < HDIM; ++k) {
            float a = my[k];
            #pragma unroll
            for (int jj = 0; jj < LDIM; ++jj) dx[jj] = fmaf(a, wm2[k*LDIM + jj], dx[jj]);
        }
        #pragma unroll
        for (int jj = 0; jj < LDIM; ++jj) { x[jj] = (x[jj] + dx[jj]) * cut; my[jj] = x[jj]; }
        float g[CDIM], nv[CDIM];
        #pragma unroll
        for (int c = 0; c < CDIM; ++c) { g[c] = 0.0f; nv[c] = 0.0f; }
        #pragma unroll 4
        for (int k = 0; k < LDIM; ++k) {
            float a = my[k];
            #pragma unroll
            for (int c = 0; c < CDIM; ++c) {
                g[c]  = fmaf(a, wg[k*CDIM + c], g[c]);
                nv[c] = fmaf(a, wn[k*CDIM + c], nv[c]);
            }
        }
        #pragma unroll
        for (int c = 0; c < CDIM; ++c) p[c] = fmaf(p[c], g[c], nv[c]);
    }

    float eo = 0.0f;
    #pragma unroll
    for (int k = 0; k < LDIM; ++k) eo = fmaf(x[k], Wout[k], eo);
    eo *= cut * (1.0f / 3.0f);
    atomicAdd(&out[ri], eo);
}

extern "C" void kernel_launch(void* const* d_in, const int* in_sizes, int n_in,
                              void* d_out, int out_size, void* d_ws, size_t ws_size,
                              hipStream_t stream) {
    const float* pos      = (const float*)d_in[0];
    const int*   species  = (const int*)  d_in[1];
    const int*   senders  = (const int*)  d_in[2];
    const int*   receivers= (const int*)  d_in[3];
    const float* W1   = (const float*)d_in[4];
    const float* b1   = (const float*)d_in[5];
    const float* W2   = (const float*)d_in[6];
    const float* b2   = (const float*)d_in[7];
    const float* Wv   = (const float*)d_in[8];
    const float* Wm1  = (const float*)d_in[9];
    const float* bm1  = (const float*)d_in[10];
    const float* Wm2  = (const float*)d_in[11];
    const float* bm2  = (const float*)d_in[12];
    const float* Wg   = (const float*)d_in[13];
    const float* Wn   = (const float*)d_in[14];
    const float* Wout = (const float*)d_in[15];

    float* out = (float*)d_out;
    int N = out_size;
    int E = in_sizes[2];

    hipMemsetAsync(out, 0, (size_t)N * sizeof(float), stream);

    size_t pos4_bytes = (size_t)N * sizeof(float4);
    size_t need_full  = pos4_bytes + TBL_BYTES;

    if (ws_size >= need_full) {
        float4* pos4 = (float4*)d_ws;
        float*  tbl  = (float*)((char*)d_ws + pos4_bytes);
        pack_pos4<<<(N + 255) / 256, 256, 0, stream>>>(pos, species, pos4, N);
        int nblocks = (NTAB + 4 + PTS - 1) / PTS;   // 4100 waves
        build_table_v2<<<nblocks, TPB_B, 0, stream>>>(
            W1, b1, W2, b2, Wv, Wm1, bm1, Wm2, bm2, Wg, Wn, Wout, tbl);
        int nthr = (E + 1) / 2;
        edge_scatter_v2<<<(nthr + TPB_E - 1) / TPB_E, TPB_E, 0, stream>>>(
            pos4, senders, receivers, tbl, out, E);
    } else if (ws_size >= TBL_BYTES) {
        float* tbl = (float*)d_ws;
        int nblocks = (NTAB + 4 + PTS - 1) / PTS;
        build_table_v2<<<nblocks, TPB_B, 0, stream>>>(
            W1, b1, W2, b2, Wv, Wm1, bm1, Wm2, bm2, Wg, Wn, Wout, tbl);
        edge_scatter_kernel<<<(E + TPB_E - 1) / TPB_E, TPB_E, 0, stream>>>(
            pos, species, senders, receivers, tbl, out, E);
    } else {
        allegro_edge_kernel<<<(E + TPB - 1) / TPB, TPB, 0, stream>>>(
            pos, species, senders, receivers,
            W1, b1, W2, b2, Wv, Wm1, bm1, Wm2, bm2, Wg, Wn, Wout, out, E);
    }
}